// Round 12
// baseline (453.549 us; speedup 1.0000x reference)
//
#include <hip/hip_runtime.h>
#include <stdint.h>

#define N_NODES 8192
#define IN_FEAT 512
#define OUT_FEAT 256
#define LOG2E 1.4426950408889634f

typedef __bf16 b16x8 __attribute__((ext_vector_type(8)));
typedef unsigned short u16x8v __attribute__((ext_vector_type(8)));
typedef float f32x4 __attribute__((ext_vector_type(4)));

static __device__ __forceinline__ unsigned short f2bf(float f) {
    union { float f; uint32_t u; } v; v.f = f;
    uint32_t r = v.u + 0x7FFFu + ((v.u >> 16) & 1u);
    return (unsigned short)(r >> 16);
}

// K_pack: adj int32 [8192][8192] -> ROW-MAJOR bitmask (8 MB). Fully coalesced.
__global__ __launch_bounds__(256) void k_pack(const int* __restrict__ adj,
                                              unsigned char* __restrict__ bitsR) {
    size_t t = (size_t)blockIdx.x * 256 + threadIdx.x;
    const int4* a4 = (const int4*)adj + t * 2;
    int4 x0 = a4[0];
    int4 x1 = a4[1];
    unsigned b = (unsigned)(x0.x != 0)
               | ((unsigned)(x0.y != 0) << 1)
               | ((unsigned)(x0.z != 0) << 2)
               | ((unsigned)(x0.w != 0) << 3)
               | ((unsigned)(x1.x != 0) << 4)
               | ((unsigned)(x1.y != 0) << 5)
               | ((unsigned)(x1.z != 0) << 6)
               | ((unsigned)(x1.w != 0) << 7);
    bitsR[t] = (unsigned char)b;
}

// K0: Wt[c][k] = bf16(W[k][c])  (256 x 512)
__global__ __launch_bounds__(256) void k0_transpose_w(const float* __restrict__ W,
                                                      unsigned short* __restrict__ Wt) {
    int tid = blockIdx.x * 256 + threadIdx.x;
    int c = tid & (OUT_FEAT - 1);
    int k = tid >> 8;
    Wt[(size_t)c * IN_FEAT + k] = f2bf(W[(size_t)k * OUT_FEAT + c]);
}

// K1: h = X @ W via bf16 MFMA. Writes hTf in MFMA-B-fragment order.
__global__ __launch_bounds__(256) void k1_hgemm(const float* __restrict__ input,
                                                const unsigned short* __restrict__ Wt,
                                                const float* __restrict__ a_vec,
                                                unsigned short* __restrict__ hTf,
                                                float* __restrict__ s1_raw,
                                                float* __restrict__ s2_raw) {
    int tid = threadIdx.x;
    int lane = tid & 63;
    int c = lane & 15, g = lane >> 4;
    int r0 = blockIdx.x * 64 + (tid >> 6) * 16;
    f32x4 acc[16];
#pragma unroll
    for (int t = 0; t < 16; ++t) acc[t] = (f32x4){0.f, 0.f, 0.f, 0.f};
    const float* arow = input + (size_t)(r0 + c) * IN_FEAT;
#pragma unroll 1
    for (int kk = 0; kk < IN_FEAT / 32; ++kk) {
        int kb = kk * 32 + 8 * g;
        float4 x0 = *(const float4*)(arow + kb);
        float4 x1 = *(const float4*)(arow + kb + 4);
        u16x8v au;
        au[0] = f2bf(x0.x); au[1] = f2bf(x0.y); au[2] = f2bf(x0.z); au[3] = f2bf(x0.w);
        au[4] = f2bf(x1.x); au[5] = f2bf(x1.y); au[6] = f2bf(x1.z); au[7] = f2bf(x1.w);
        b16x8 af = __builtin_bit_cast(b16x8, au);
#pragma unroll
        for (int t = 0; t < 16; ++t) {
            b16x8 bf = __builtin_bit_cast(b16x8,
                *(const u16x8v*)(Wt + (size_t)(16 * t + c) * IN_FEAT + kb));
            acc[t] = __builtin_amdgcn_mfma_f32_16x16x32_bf16(af, bf, acc[t], 0, 0, 0);
        }
    }
    float a1v[16], a2v[16];
#pragma unroll
    for (int t = 0; t < 16; ++t) {
        a1v[t] = a_vec[16 * t + c];
        a2v[t] = a_vec[OUT_FEAT + 16 * t + c];
    }
#pragma unroll
    for (int r = 0; r < 4; ++r) {
        float s1p = 0.f, s2p = 0.f;
#pragma unroll
        for (int t = 0; t < 16; ++t) { s1p += acc[t][r] * a1v[t]; s2p += acc[t][r] * a2v[t]; }
#pragma unroll
        for (int m = 1; m <= 8; m <<= 1) { s1p += __shfl_xor(s1p, m); s2p += __shfl_xor(s2p, m); }
        if (c == 0) {
            int row = r0 + 4 * g + r;
            s1_raw[row] = s1p;
            s2_raw[row] = s2p;
        }
    }
    int chunk = r0 >> 5;
    int lp = ((r0 & 16) >> 3) + (g >> 1);
    int e0 = 4 * (g & 1);
#pragma unroll
    for (int t = 0; t < 16; ++t) {
        ushort4 pk;
        pk.x = f2bf(acc[t][0]); pk.y = f2bf(acc[t][1]);
        pk.z = f2bf(acc[t][2]); pk.w = f2bf(acc[t][3]);
        *(ushort4*)(hTf + ((size_t)(chunk * 16 + t) * 64 + lp * 16 + c) * 8 + e0) = pk;
    }
}

// K2: factored-exp constants.
__global__ __launch_bounds__(256) void k2_prep(const float* __restrict__ s1_raw,
                                               const float* __restrict__ s2_raw,
                                               float* __restrict__ e12,
                                               float2* __restrict__ row2) {
    __shared__ float red[256];
    int tid = threadIdx.x;
    float m = -3.0e38f;
    for (int j = tid; j < N_NODES; j += 256) m = fmaxf(m, s2_raw[j]);
    red[tid] = m;
    __syncthreads();
    for (int s = 128; s > 0; s >>= 1) {
        if (tid < s) red[tid] = fmaxf(red[tid], red[tid + s]);
        __syncthreads();
    }
    float M2 = red[0];
    int i = blockIdx.x * 256 + tid;
    float s1 = s1_raw[i];
    float u = s1 + M2;
    float mi = fmaxf(u, 0.2f * u);                 // per-row upper bound on e
    row2[i] = make_float2(__builtin_amdgcn_exp2f((s1 - mi) * LOG2E),
                          __builtin_amdgcn_exp2f((0.2f * s1 - mi) * LOG2E));
    float s2 = s2_raw[i];
    e12[2 * i]     = __builtin_amdgcn_exp2f(s2 * LOG2E);
    e12[2 * i + 1] = __builtin_amdgcn_exp2f(0.2f * s2 * LOG2E);
}

// K3 v11: barrier-free flash-GAT partials at 4 waves/SIMD.
// Grid 512 = 128 rowgroups (64 rows) x 4 jq. 512 threads = 8 waves:
// (js 0..1) x (rq 0..1) x (ch 0..1). Wave: 32 rows (dual A-frag) x 128 cols
// x 32 chunks (its j-half). Inner loop identical to v10 (measured); js pairs
// merge acc via LDS at the END (2 rounds, 4 barriers total).
__global__ __launch_bounds__(512, 4) void k3_flash(const uint32_t* __restrict__ maskR,
                                                   const unsigned short* __restrict__ hTf,
                                                   const float* __restrict__ e12g,
                                                   const float2* __restrict__ row2,
                                                   float* __restrict__ pout,
                                                   float* __restrict__ rowpart) {
    __shared__ __align__(16) float le12[4096];               // 16 KB
    __shared__ __align__(16) float sred[8192];               // 32 KB acc staging
    __shared__ float ldsL[2][64];                            // row-sum halves

    int tid = threadIdx.x;
    int w = tid >> 6, lane = tid & 63;
    int c = lane & 15, g = lane >> 4;
    int ch = w & 1, rq = (w >> 1) & 1, js = w >> 2;
    int jq = blockIdx.x & 3;
    int rg = blockIdx.x >> 2;
    int rowbase = rg * 64 + rq * 32;

    // prologue: stage e12 quarter (8 floats/thread), one barrier
    *(float4*)&le12[tid * 8]     = *(const float4*)(e12g + (size_t)jq * 4096 + tid * 8);
    *(float4*)&le12[tid * 8 + 4] = *(const float4*)(e12g + (size_t)jq * 4096 + tid * 8 + 4);
    float2 rc0 = row2[rowbase + c];
    float2 rc1 = row2[rowbase + 16 + c];
    float E1r0 = rc0.x, E2r0 = rc0.y;
    float E1r1 = rc1.x, E2r1 = rc1.y;
    __syncthreads();

    // mask pointers: maskR as int4 rows of 64 (256 dwords/row)
    const int4* m4_0 = (const int4*)maskR + (size_t)(rowbase + c) * 64 + jq * 16 + js * 8;
    const int4* m4_1 = (const int4*)maskR + (size_t)(rowbase + 16 + c) * 64 + jq * 16 + js * 8;

    f32x4 acc0[8], acc1[8];
#pragma unroll
    for (int t = 0; t < 8; ++t) { acc0[t] = (f32x4){0,0,0,0}; acc1[t] = (f32x4){0,0,0,0}; }
    float lacc0 = 0.f, lacc1 = 0.f;

#pragma unroll 2
    for (int kk4 = 0; kk4 < 8; ++kk4) {
        int4 mq0 = m4_0[kk4];        // masks for 4 chunks, rowset 0
        int4 mq1 = m4_1[kk4];        // rowset 1
        uint32_t md0[4] = {(uint32_t)mq0.x, (uint32_t)mq0.y, (uint32_t)mq0.z, (uint32_t)mq0.w};
        uint32_t md1[4] = {(uint32_t)mq1.x, (uint32_t)mq1.y, (uint32_t)mq1.z, (uint32_t)mq1.w};
#pragma unroll
        for (int sub = 0; sub < 4; ++sub) {
            int kk = js * 32 + kk4 * 4 + sub;
            int jchunk = jq * 64 + kk;
            uint32_t mb0 = (md0[sub] >> (8 * g)) & 0xFFu;
            uint32_t mb1 = (md1[sub] >> (8 * g)) & 0xFFu;
            float ev[16];
#pragma unroll
            for (int q = 0; q < 4; ++q)
                *(f32x4*)&ev[q * 4] = *(const f32x4*)&le12[(kk * 32 + 8 * g) * 2 + q * 4];
            b16x8 af0, af1;
#pragma unroll
            for (int e = 0; e < 8; ++e) {
                float e1 = ev[2 * e], e2 = ev[2 * e + 1];
                float q0 = fmaxf(E1r0 * e1, E2r0 * e2);
                float p0 = (mb0 & (1u << e)) ? q0 : 0.f;
                lacc0 += p0;
                af0[e] = (__bf16)p0;
                float q1 = fmaxf(E1r1 * e1, E2r1 * e2);
                float p1 = (mb1 & (1u << e)) ? q1 : 0.f;
                lacc1 += p1;
                af1[e] = (__bf16)p1;
            }
            const unsigned short* tb = hTf + (size_t)(jchunk * 16 + ch * 8) * 512 + lane * 8;
#pragma unroll
            for (int t = 0; t < 8; ++t) {
                b16x8 bf = __builtin_bit_cast(b16x8, *(const u16x8v*)(tb + t * 512));
                acc0[t] = __builtin_amdgcn_mfma_f32_16x16x32_bf16(af0, bf, acc0[t], 0, 0, 0);
                acc1[t] = __builtin_amdgcn_mfma_f32_16x16x32_bf16(af1, bf, acc1[t], 0, 0, 0);
            }
        }
    }

    // per-wave row sums for this j-half
    float l0 = lacc0 + __shfl_xor(lacc0, 16); l0 += __shfl_xor(l0, 32);
    float l1 = lacc1 + __shfl_xor(lacc1, 16); l1 += __shfl_xor(l1, 32);
    if (ch == 0 && g == 0) {
        ldsL[js][rq * 32 + c] = l0;
        ldsL[js][rq * 32 + 16 + c] = l1;
    }

    // merge js halves: round 1 (acc0), round 2 (acc1)
    float* reg = &sred[(rq * 2 + ch) * 2048];
    if (js == 1) {
#pragma unroll
        for (int t = 0; t < 8; ++t) *(f32x4*)(reg + (t * 64 + lane) * 4) = acc0[t];
    }
    __syncthreads();
    if (js == 0) {
#pragma unroll
        for (int t = 0; t < 8; ++t) acc0[t] += *(const f32x4*)(reg + (t * 64 + lane) * 4);
    }
    __syncthreads();
    if (js == 1) {
#pragma unroll
        for (int t = 0; t < 8; ++t) *(f32x4*)(reg + (t * 64 + lane) * 4) = acc1[t];
    }
    __syncthreads();
    if (js == 0) {
#pragma unroll
        for (int t = 0; t < 8; ++t) acc1[t] += *(const f32x4*)(reg + (t * 64 + lane) * 4);

        if (ch == 0 && g == 0) {
            rowpart[jq * N_NODES + rowbase + c] = ldsL[0][rq * 32 + c] + ldsL[1][rq * 32 + c];
            rowpart[jq * N_NODES + rowbase + 16 + c] =
                ldsL[0][rq * 32 + 16 + c] + ldsL[1][rq * 32 + 16 + c];
        }
#pragma unroll
        for (int r = 0; r < 4; ++r) {
            int grow0 = rowbase + 4 * g + r;        // C layout: row=(lane>>4)*4+reg
            int grow1 = grow0 + 16;
#pragma unroll
            for (int t = 0; t < 8; ++t) {
                pout[((size_t)jq * N_NODES + grow0) * OUT_FEAT + ch * 128 + 16 * t + c] = acc0[t][r];
                pout[((size_t)jq * N_NODES + grow1) * OUT_FEAT + ch * 128 + 16 * t + c] = acc1[t][r];
            }
        }
    }
}

// K4: out = elu( (sum_q pout[q]) / (sum_q rowpart[q]) ).
__global__ __launch_bounds__(256) void k4_reduce(const float* __restrict__ pout,
                                                 const float* __restrict__ rowpart,
                                                 float* __restrict__ out) {
    int t = blockIdx.x * 256 + threadIdx.x;
    int row = t >> 8;
    float s = 0.f, l = 0.f;
#pragma unroll
    for (int q = 0; q < 4; ++q) {
        s += pout[(size_t)q * N_NODES * OUT_FEAT + t];
        l += rowpart[q * N_NODES + row];
    }
    float inv = (l > 0.f) ? 1.0f / l : 0.f;
    float x = s * inv;
    out[t] = (x > 0.f) ? x : (__builtin_amdgcn_exp2f(x * LOG2E) - 1.0f);
}

extern "C" void kernel_launch(void* const* d_in, const int* in_sizes, int n_in,
                              void* d_out, int out_size, void* d_ws, size_t ws_size,
                              hipStream_t stream) {
    const float* input = (const float*)d_in[0];
    const int* adj = (const int*)d_in[1];
    const float* W = (const float*)d_in[2];
    const float* a_vec = (const float*)d_in[3];
    float* out = (float*)d_out;

    char* ws = (char*)d_ws;
    unsigned short* Wt  = (unsigned short*)(ws);                 // 256 KB
    unsigned short* hTf = (unsigned short*)(ws + 262144);        // 4 MB
    float*  e12     = (float*)(ws + 4456448);                    // 64 KB
    float2* row2    = (float2*)(ws + 4521984);                   // 64 KB
    float*  s1_raw  = (float*)(ws + 4587520);                    // 32 KB
    float*  s2_raw  = (float*)(ws + 4620288);                    // 32 KB
    unsigned char* bitsR = (unsigned char*)(ws + 4653056);       // 8 MB
    float*  rowpart = (float*)(ws + 13041664);                   // 128 KB
    float*  pout    = (float*)(ws + 13172736);                   // 32 MB

    hipLaunchKernelGGL(k_pack, dim3(32768), dim3(256), 0, stream, adj, bitsR);
    hipLaunchKernelGGL(k0_transpose_w, dim3(512), dim3(256), 0, stream, W, Wt);
    hipLaunchKernelGGL(k1_hgemm, dim3(N_NODES / 64), dim3(256), 0, stream,
                       input, Wt, a_vec, hTf, s1_raw, s2_raw);
    hipLaunchKernelGGL(k2_prep, dim3(32), dim3(256), 0, stream, s1_raw, s2_raw, e12, row2);
    hipLaunchKernelGGL(k3_flash, dim3(512), dim3(512), 0, stream,
                       (const uint32_t*)bitsR, hTf, e12, row2, pout, rowpart);
    hipLaunchKernelGGL(k4_reduce, dim3(N_NODES * OUT_FEAT / 256), dim3(256), 0, stream,
                       pout, rowpart, out);
}

// Round 13
// 337.428 us; speedup vs baseline: 1.3441x; 1.3441x over previous
//
#include <hip/hip_runtime.h>
#include <stdint.h>

#define N_NODES 8192
#define IN_FEAT 512
#define OUT_FEAT 256
#define LOG2E 1.4426950408889634f

typedef __bf16 b16x8 __attribute__((ext_vector_type(8)));
typedef unsigned short u16x8v __attribute__((ext_vector_type(8)));
typedef float f32x4 __attribute__((ext_vector_type(4)));

static __device__ __forceinline__ unsigned short f2bf(float f) {
    union { float f; uint32_t u; } v; v.f = f;
    uint32_t r = v.u + 0x7FFFu + ((v.u >> 16) & 1u);
    return (unsigned short)(r >> 16);
}

// K_pack: adj int32 [8192][8192] -> ROW-MAJOR bitmask (8 MB). Fully coalesced.
__global__ __launch_bounds__(256) void k_pack(const int* __restrict__ adj,
                                              unsigned char* __restrict__ bitsR) {
    size_t t = (size_t)blockIdx.x * 256 + threadIdx.x;
    const int4* a4 = (const int4*)adj + t * 2;
    int4 x0 = a4[0];
    int4 x1 = a4[1];
    unsigned b = (unsigned)(x0.x != 0)
               | ((unsigned)(x0.y != 0) << 1)
               | ((unsigned)(x0.z != 0) << 2)
               | ((unsigned)(x0.w != 0) << 3)
               | ((unsigned)(x1.x != 0) << 4)
               | ((unsigned)(x1.y != 0) << 5)
               | ((unsigned)(x1.z != 0) << 6)
               | ((unsigned)(x1.w != 0) << 7);
    bitsR[t] = (unsigned char)b;
}

// K0: Wt[c][k] = bf16(W[k][c])  (256 x 512)
__global__ __launch_bounds__(256) void k0_transpose_w(const float* __restrict__ W,
                                                      unsigned short* __restrict__ Wt) {
    int tid = blockIdx.x * 256 + threadIdx.x;
    int c = tid & (OUT_FEAT - 1);
    int k = tid >> 8;
    Wt[(size_t)c * IN_FEAT + k] = f2bf(W[(size_t)k * OUT_FEAT + c]);
}

// K1: h = X @ W via bf16 MFMA. Writes hTf in MFMA-B-fragment order.
__global__ __launch_bounds__(256) void k1_hgemm(const float* __restrict__ input,
                                                const unsigned short* __restrict__ Wt,
                                                const float* __restrict__ a_vec,
                                                unsigned short* __restrict__ hTf,
                                                float* __restrict__ s1_raw,
                                                float* __restrict__ s2_raw) {
    int tid = threadIdx.x;
    int lane = tid & 63;
    int c = lane & 15, g = lane >> 4;
    int r0 = blockIdx.x * 64 + (tid >> 6) * 16;
    f32x4 acc[16];
#pragma unroll
    for (int t = 0; t < 16; ++t) acc[t] = (f32x4){0.f, 0.f, 0.f, 0.f};
    const float* arow = input + (size_t)(r0 + c) * IN_FEAT;
#pragma unroll 1
    for (int kk = 0; kk < IN_FEAT / 32; ++kk) {
        int kb = kk * 32 + 8 * g;
        float4 x0 = *(const float4*)(arow + kb);
        float4 x1 = *(const float4*)(arow + kb + 4);
        u16x8v au;
        au[0] = f2bf(x0.x); au[1] = f2bf(x0.y); au[2] = f2bf(x0.z); au[3] = f2bf(x0.w);
        au[4] = f2bf(x1.x); au[5] = f2bf(x1.y); au[6] = f2bf(x1.z); au[7] = f2bf(x1.w);
        b16x8 af = __builtin_bit_cast(b16x8, au);
#pragma unroll
        for (int t = 0; t < 16; ++t) {
            b16x8 bf = __builtin_bit_cast(b16x8,
                *(const u16x8v*)(Wt + (size_t)(16 * t + c) * IN_FEAT + kb));
            acc[t] = __builtin_amdgcn_mfma_f32_16x16x32_bf16(af, bf, acc[t], 0, 0, 0);
        }
    }
    float a1v[16], a2v[16];
#pragma unroll
    for (int t = 0; t < 16; ++t) {
        a1v[t] = a_vec[16 * t + c];
        a2v[t] = a_vec[OUT_FEAT + 16 * t + c];
    }
#pragma unroll
    for (int r = 0; r < 4; ++r) {
        float s1p = 0.f, s2p = 0.f;
#pragma unroll
        for (int t = 0; t < 16; ++t) { s1p += acc[t][r] * a1v[t]; s2p += acc[t][r] * a2v[t]; }
#pragma unroll
        for (int m = 1; m <= 8; m <<= 1) { s1p += __shfl_xor(s1p, m); s2p += __shfl_xor(s2p, m); }
        if (c == 0) {
            int row = r0 + 4 * g + r;
            s1_raw[row] = s1p;
            s2_raw[row] = s2p;
        }
    }
    int chunk = r0 >> 5;
    int lp = ((r0 & 16) >> 3) + (g >> 1);
    int e0 = 4 * (g & 1);
#pragma unroll
    for (int t = 0; t < 16; ++t) {
        ushort4 pk;
        pk.x = f2bf(acc[t][0]); pk.y = f2bf(acc[t][1]);
        pk.z = f2bf(acc[t][2]); pk.w = f2bf(acc[t][3]);
        *(ushort4*)(hTf + ((size_t)(chunk * 16 + t) * 64 + lp * 16 + c) * 8 + e0) = pk;
    }
}

// K2: factored-exp constants.
__global__ __launch_bounds__(256) void k2_prep(const float* __restrict__ s1_raw,
                                               const float* __restrict__ s2_raw,
                                               float* __restrict__ e12,
                                               float2* __restrict__ row2) {
    __shared__ float red[256];
    int tid = threadIdx.x;
    float m = -3.0e38f;
    for (int j = tid; j < N_NODES; j += 256) m = fmaxf(m, s2_raw[j]);
    red[tid] = m;
    __syncthreads();
    for (int s = 128; s > 0; s >>= 1) {
        if (tid < s) red[tid] = fmaxf(red[tid], red[tid + s]);
        __syncthreads();
    }
    float M2 = red[0];
    int i = blockIdx.x * 256 + tid;
    float s1 = s1_raw[i];
    float u = s1 + M2;
    float mi = fmaxf(u, 0.2f * u);                 // per-row upper bound on e
    row2[i] = make_float2(__builtin_amdgcn_exp2f((s1 - mi) * LOG2E),
                          __builtin_amdgcn_exp2f((0.2f * s1 - mi) * LOG2E));
    float s2 = s2_raw[i];
    e12[2 * i]     = __builtin_amdgcn_exp2f(s2 * LOG2E);
    e12[2 * i + 1] = __builtin_amdgcn_exp2f(0.2f * s2 * LOG2E);
}

// K3 v12: barrier-free flash-GAT partials, 16 waves/CU via grid (not block size).
// Grid 1024 = 256 rowgroups (32 rows) x 4 jq. Block = 128 threads = 2 waves
// (ch 0/1). Wave: 32 rows (dual A-frag) x 128 cols x 64 chunks. No cross-wave
// merge. b-frag loads explicitly batched 4-at-a-time so L2 latency is exposed
// once per batch, not once per MFMA pair. 8 blocks/CU -> ~50% occupancy.
__global__ __launch_bounds__(128, 4) void k3_flash(const uint32_t* __restrict__ maskR,
                                                   const unsigned short* __restrict__ hTf,
                                                   const float* __restrict__ e12g,
                                                   const float2* __restrict__ row2,
                                                   float* __restrict__ pout,
                                                   float* __restrict__ rowpart) {
    __shared__ __align__(16) float le12[4096];               // 16 KB

    int tid = threadIdx.x;
    int ch = tid >> 6, lane = tid & 63;
    int c = lane & 15, g = lane >> 4;
    int jq = blockIdx.x & 3;
    int rg = blockIdx.x >> 2;
    int rowbase = rg * 32;

    // prologue: stage e12 quarter (32 floats/thread), one barrier
#pragma unroll
    for (int q = 0; q < 8; ++q) {
        *(float4*)&le12[tid * 32 + q * 4] =
            *(const float4*)(e12g + (size_t)jq * 4096 + tid * 32 + q * 4);
    }
    float2 rc0 = row2[rowbase + c];
    float2 rc1 = row2[rowbase + 16 + c];
    float E1r0 = rc0.x, E2r0 = rc0.y;
    float E1r1 = rc1.x, E2r1 = rc1.y;
    __syncthreads();

    // mask pointers: maskR as int4 rows of 64 (256 dwords/row)
    const int4* m4_0 = (const int4*)maskR + (size_t)(rowbase + c) * 64 + jq * 16;
    const int4* m4_1 = (const int4*)maskR + (size_t)(rowbase + 16 + c) * 64 + jq * 16;

    f32x4 acc0[8], acc1[8];
#pragma unroll
    for (int t = 0; t < 8; ++t) { acc0[t] = (f32x4){0,0,0,0}; acc1[t] = (f32x4){0,0,0,0}; }
    float lacc0 = 0.f, lacc1 = 0.f;

#pragma unroll 1
    for (int kk4 = 0; kk4 < 16; ++kk4) {
        int4 mq0 = m4_0[kk4];        // masks for 4 chunks, rowset 0
        int4 mq1 = m4_1[kk4];        // rowset 1
        uint32_t md0[4] = {(uint32_t)mq0.x, (uint32_t)mq0.y, (uint32_t)mq0.z, (uint32_t)mq0.w};
        uint32_t md1[4] = {(uint32_t)mq1.x, (uint32_t)mq1.y, (uint32_t)mq1.z, (uint32_t)mq1.w};
#pragma unroll
        for (int sub = 0; sub < 4; ++sub) {
            int kk = kk4 * 4 + sub;
            int jchunk = jq * 64 + kk;
            const unsigned short* tb = hTf + (size_t)(jchunk * 16 + ch * 8) * 512 + lane * 8;

            // phase 1: batch-issue b-frags 0..3 (in flight during score compute)
            b16x8 bfv[4];
#pragma unroll
            for (int t = 0; t < 4; ++t)
                bfv[t] = __builtin_bit_cast(b16x8, *(const u16x8v*)(tb + t * 512));

            // score for 2 rowsets x 8 js (ev from LDS, register-light)
            uint32_t mb0 = (md0[sub] >> (8 * g)) & 0xFFu;
            uint32_t mb1 = (md1[sub] >> (8 * g)) & 0xFFu;
            b16x8 af0, af1;
#pragma unroll
            for (int e = 0; e < 8; ++e) {
                float2 ep = *(const float2*)&le12[(kk * 32 + 8 * g + e) * 2];
                float q0 = fmaxf(E1r0 * ep.x, E2r0 * ep.y);
                float p0 = (mb0 & (1u << e)) ? q0 : 0.f;
                lacc0 += p0;
                af0[e] = (__bf16)p0;
                float q1 = fmaxf(E1r1 * ep.x, E2r1 * ep.y);
                float p1 = (mb1 & (1u << e)) ? q1 : 0.f;
                lacc1 += p1;
                af1[e] = (__bf16)p1;
            }

            // mfma 0..3
#pragma unroll
            for (int t = 0; t < 4; ++t) {
                acc0[t] = __builtin_amdgcn_mfma_f32_16x16x32_bf16(af0, bfv[t], acc0[t], 0, 0, 0);
                acc1[t] = __builtin_amdgcn_mfma_f32_16x16x32_bf16(af1, bfv[t], acc1[t], 0, 0, 0);
            }
            // phase 2: batch-issue b-frags 4..7, then mfma
            b16x8 bfw[4];
#pragma unroll
            for (int t = 0; t < 4; ++t)
                bfw[t] = __builtin_bit_cast(b16x8, *(const u16x8v*)(tb + (t + 4) * 512));
#pragma unroll
            for (int t = 0; t < 4; ++t) {
                acc0[t + 4] = __builtin_amdgcn_mfma_f32_16x16x32_bf16(af0, bfw[t], acc0[t + 4], 0, 0, 0);
                acc1[t + 4] = __builtin_amdgcn_mfma_f32_16x16x32_bf16(af1, bfw[t], acc1[t + 4], 0, 0, 0);
            }
        }
    }

    // row sums over this j-quarter (lanes c,c+16,c+32,c+48 cover all g-octets)
    float l0 = lacc0 + __shfl_xor(lacc0, 16); l0 += __shfl_xor(l0, 32);
    float l1 = lacc1 + __shfl_xor(lacc1, 16); l1 += __shfl_xor(l1, 32);
    if (ch == 0 && g == 0) {
        rowpart[jq * N_NODES + rowbase + c] = l0;
        rowpart[jq * N_NODES + rowbase + 16 + c] = l1;
    }

#pragma unroll
    for (int r = 0; r < 4; ++r) {
        int grow0 = rowbase + 4 * g + r;        // C layout: row=(lane>>4)*4+reg
        int grow1 = grow0 + 16;
#pragma unroll
        for (int t = 0; t < 8; ++t) {
            pout[((size_t)jq * N_NODES + grow0) * OUT_FEAT + ch * 128 + 16 * t + c] = acc0[t][r];
            pout[((size_t)jq * N_NODES + grow1) * OUT_FEAT + ch * 128 + 16 * t + c] = acc1[t][r];
        }
    }
}

// K4: out = elu( (sum_q pout[q]) / (sum_q rowpart[q]) ).
__global__ __launch_bounds__(256) void k4_reduce(const float* __restrict__ pout,
                                                 const float* __restrict__ rowpart,
                                                 float* __restrict__ out) {
    int t = blockIdx.x * 256 + threadIdx.x;
    int row = t >> 8;
    float s = 0.f, l = 0.f;
#pragma unroll
    for (int q = 0; q < 4; ++q) {
        s += pout[(size_t)q * N_NODES * OUT_FEAT + t];
        l += rowpart[q * N_NODES + row];
    }
    float inv = (l > 0.f) ? 1.0f / l : 0.f;
    float x = s * inv;
    out[t] = (x > 0.f) ? x : (__builtin_amdgcn_exp2f(x * LOG2E) - 1.0f);
}

extern "C" void kernel_launch(void* const* d_in, const int* in_sizes, int n_in,
                              void* d_out, int out_size, void* d_ws, size_t ws_size,
                              hipStream_t stream) {
    const float* input = (const float*)d_in[0];
    const int* adj = (const int*)d_in[1];
    const float* W = (const float*)d_in[2];
    const float* a_vec = (const float*)d_in[3];
    float* out = (float*)d_out;

    char* ws = (char*)d_ws;
    unsigned short* Wt  = (unsigned short*)(ws);                 // 256 KB
    unsigned short* hTf = (unsigned short*)(ws + 262144);        // 4 MB
    float*  e12     = (float*)(ws + 4456448);                    // 64 KB
    float2* row2    = (float2*)(ws + 4521984);                   // 64 KB
    float*  s1_raw  = (float*)(ws + 4587520);                    // 32 KB
    float*  s2_raw  = (float*)(ws + 4620288);                    // 32 KB
    unsigned char* bitsR = (unsigned char*)(ws + 4653056);       // 8 MB
    float*  rowpart = (float*)(ws + 13041664);                   // 128 KB
    float*  pout    = (float*)(ws + 13172736);                   // 32 MB

    hipLaunchKernelGGL(k_pack, dim3(32768), dim3(256), 0, stream, adj, bitsR);
    hipLaunchKernelGGL(k0_transpose_w, dim3(512), dim3(256), 0, stream, W, Wt);
    hipLaunchKernelGGL(k1_hgemm, dim3(N_NODES / 64), dim3(256), 0, stream,
                       input, Wt, a_vec, hTf, s1_raw, s2_raw);
    hipLaunchKernelGGL(k2_prep, dim3(32), dim3(256), 0, stream, s1_raw, s2_raw, e12, row2);
    hipLaunchKernelGGL(k3_flash, dim3(1024), dim3(128), 0, stream,
                       (const uint32_t*)bitsR, hTf, e12, row2, pout, rowpart);
    hipLaunchKernelGGL(k4_reduce, dim3(N_NODES * OUT_FEAT / 256), dim3(256), 0, stream,
                       pout, rowpart, out);
}

// Round 14
// 185.674 us; speedup vs baseline: 2.4427x; 1.8173x over previous
//
#include <hip/hip_runtime.h>
#include <stdint.h>

#define N_NODES 8192
#define IN_FEAT 512
#define OUT_FEAT 256
#define LOG2E 1.4426950408889634f

typedef __bf16 b16x8 __attribute__((ext_vector_type(8)));
typedef unsigned short u16x8v __attribute__((ext_vector_type(8)));
typedef float f32x4 __attribute__((ext_vector_type(4)));

static __device__ __forceinline__ unsigned short f2bf(float f) {
    union { float f; uint32_t u; } v; v.f = f;
    uint32_t r = v.u + 0x7FFFu + ((v.u >> 16) & 1u);
    return (unsigned short)(r >> 16);
}

// K_pack: adj int32 [8192][8192] -> ROW-MAJOR bitmask (8 MB). Fully coalesced.
__global__ __launch_bounds__(256) void k_pack(const int* __restrict__ adj,
                                              unsigned char* __restrict__ bitsR) {
    size_t t = (size_t)blockIdx.x * 256 + threadIdx.x;
    const int4* a4 = (const int4*)adj + t * 2;
    int4 x0 = a4[0];
    int4 x1 = a4[1];
    unsigned b = (unsigned)(x0.x != 0)
               | ((unsigned)(x0.y != 0) << 1)
               | ((unsigned)(x0.z != 0) << 2)
               | ((unsigned)(x0.w != 0) << 3)
               | ((unsigned)(x1.x != 0) << 4)
               | ((unsigned)(x1.y != 0) << 5)
               | ((unsigned)(x1.z != 0) << 6)
               | ((unsigned)(x1.w != 0) << 7);
    bitsR[t] = (unsigned char)b;
}

// K0: Wt[c][k] = bf16(W[k][c])  (256 x 512)
__global__ __launch_bounds__(256) void k0_transpose_w(const float* __restrict__ W,
                                                      unsigned short* __restrict__ Wt) {
    int tid = blockIdx.x * 256 + threadIdx.x;
    int c = tid & (OUT_FEAT - 1);
    int k = tid >> 8;
    Wt[(size_t)c * IN_FEAT + k] = f2bf(W[(size_t)k * OUT_FEAT + c]);
}

// K1: h = X @ W via bf16 MFMA. Writes hTf in MFMA-B-fragment order.
__global__ __launch_bounds__(256) void k1_hgemm(const float* __restrict__ input,
                                                const unsigned short* __restrict__ Wt,
                                                const float* __restrict__ a_vec,
                                                unsigned short* __restrict__ hTf,
                                                float* __restrict__ s1_raw,
                                                float* __restrict__ s2_raw) {
    int tid = threadIdx.x;
    int lane = tid & 63;
    int c = lane & 15, g = lane >> 4;
    int r0 = blockIdx.x * 64 + (tid >> 6) * 16;
    f32x4 acc[16];
#pragma unroll
    for (int t = 0; t < 16; ++t) acc[t] = (f32x4){0.f, 0.f, 0.f, 0.f};
    const float* arow = input + (size_t)(r0 + c) * IN_FEAT;
#pragma unroll 1
    for (int kk = 0; kk < IN_FEAT / 32; ++kk) {
        int kb = kk * 32 + 8 * g;
        float4 x0 = *(const float4*)(arow + kb);
        float4 x1 = *(const float4*)(arow + kb + 4);
        u16x8v au;
        au[0] = f2bf(x0.x); au[1] = f2bf(x0.y); au[2] = f2bf(x0.z); au[3] = f2bf(x0.w);
        au[4] = f2bf(x1.x); au[5] = f2bf(x1.y); au[6] = f2bf(x1.z); au[7] = f2bf(x1.w);
        b16x8 af = __builtin_bit_cast(b16x8, au);
#pragma unroll
        for (int t = 0; t < 16; ++t) {
            b16x8 bf = __builtin_bit_cast(b16x8,
                *(const u16x8v*)(Wt + (size_t)(16 * t + c) * IN_FEAT + kb));
            acc[t] = __builtin_amdgcn_mfma_f32_16x16x32_bf16(af, bf, acc[t], 0, 0, 0);
        }
    }
    float a1v[16], a2v[16];
#pragma unroll
    for (int t = 0; t < 16; ++t) {
        a1v[t] = a_vec[16 * t + c];
        a2v[t] = a_vec[OUT_FEAT + 16 * t + c];
    }
#pragma unroll
    for (int r = 0; r < 4; ++r) {
        float s1p = 0.f, s2p = 0.f;
#pragma unroll
        for (int t = 0; t < 16; ++t) { s1p += acc[t][r] * a1v[t]; s2p += acc[t][r] * a2v[t]; }
#pragma unroll
        for (int m = 1; m <= 8; m <<= 1) { s1p += __shfl_xor(s1p, m); s2p += __shfl_xor(s2p, m); }
        if (c == 0) {
            int row = r0 + 4 * g + r;
            s1_raw[row] = s1p;
            s2_raw[row] = s2p;
        }
    }
    int chunk = r0 >> 5;
    int lp = ((r0 & 16) >> 3) + (g >> 1);
    int e0 = 4 * (g & 1);
#pragma unroll
    for (int t = 0; t < 16; ++t) {
        ushort4 pk;
        pk.x = f2bf(acc[t][0]); pk.y = f2bf(acc[t][1]);
        pk.z = f2bf(acc[t][2]); pk.w = f2bf(acc[t][3]);
        *(ushort4*)(hTf + ((size_t)(chunk * 16 + t) * 64 + lp * 16 + c) * 8 + e0) = pk;
    }
}

// K2: factored-exp constants.
__global__ __launch_bounds__(256) void k2_prep(const float* __restrict__ s1_raw,
                                               const float* __restrict__ s2_raw,
                                               float* __restrict__ e12,
                                               float2* __restrict__ row2) {
    __shared__ float red[256];
    int tid = threadIdx.x;
    float m = -3.0e38f;
    for (int j = tid; j < N_NODES; j += 256) m = fmaxf(m, s2_raw[j]);
    red[tid] = m;
    __syncthreads();
    for (int s = 128; s > 0; s >>= 1) {
        if (tid < s) red[tid] = fmaxf(red[tid], red[tid + s]);
        __syncthreads();
    }
    float M2 = red[0];
    int i = blockIdx.x * 256 + tid;
    float s1 = s1_raw[i];
    float u = s1 + M2;
    float mi = fmaxf(u, 0.2f * u);                 // per-row upper bound on e
    row2[i] = make_float2(__builtin_amdgcn_exp2f((s1 - mi) * LOG2E),
                          __builtin_amdgcn_exp2f((0.2f * s1 - mi) * LOG2E));
    float s2 = s2_raw[i];
    e12[2 * i]     = __builtin_amdgcn_exp2f(s2 * LOG2E);
    e12[2 * i + 1] = __builtin_amdgcn_exp2f(0.2f * s2 * LOG2E);
}

// K3 v13: barrier-free flash-GAT partials, single A-frag, REGISTER-SAFE 4 waves/SIMD.
// Grid 1024 = 256 rowgroups (32 rows) x 4 jq. Block = 256 threads = 4 waves
// (rq 0/1 x ch 0/1). Wave: 16 rows x 128 cols x 64 chunks, acc[8]=32 regs ->
// ~100 total regs/wave, fits the 128-reg budget at 4 waves/SIMD (R12/R13 spilled
// because dual-frag needs ~190). b-frag loads batched 4-at-a-time.
__global__ __launch_bounds__(256, 4) void k3_flash(const uint32_t* __restrict__ maskR,
                                                   const unsigned short* __restrict__ hTf,
                                                   const float* __restrict__ e12g,
                                                   const float2* __restrict__ row2,
                                                   float* __restrict__ pout,
                                                   float* __restrict__ rowpart) {
    __shared__ __align__(16) float le12[4096];               // 16 KB

    int tid = threadIdx.x;
    int w = tid >> 6, lane = tid & 63;
    int c = lane & 15, g = lane >> 4;
    int ch = w & 1, rq = w >> 1;
    int jq = blockIdx.x & 3;
    int rg = blockIdx.x >> 2;
    int rowbase = rg * 32 + rq * 16;

    // prologue: stage e12 quarter (16 floats/thread), one barrier
#pragma unroll
    for (int q = 0; q < 4; ++q) {
        *(float4*)&le12[tid * 16 + q * 4] =
            *(const float4*)(e12g + (size_t)jq * 4096 + tid * 16 + q * 4);
    }
    float2 rc0 = row2[rowbase + c];
    float E1r0 = rc0.x, E2r0 = rc0.y;
    __syncthreads();

    // mask pointer: maskR as int4 rows of 64 (256 dwords/row)
    const int4* m4_0 = (const int4*)maskR + (size_t)(rowbase + c) * 64 + jq * 16;

    f32x4 acc0[8];
#pragma unroll
    for (int t = 0; t < 8; ++t) acc0[t] = (f32x4){0, 0, 0, 0};
    float lacc0 = 0.f;

#pragma unroll 1
    for (int kk4 = 0; kk4 < 16; ++kk4) {
        int4 mq0 = m4_0[kk4];        // masks for 4 chunks
        uint32_t md0[4] = {(uint32_t)mq0.x, (uint32_t)mq0.y, (uint32_t)mq0.z, (uint32_t)mq0.w};
#pragma unroll
        for (int sub = 0; sub < 4; ++sub) {
            int kk = kk4 * 4 + sub;
            int jchunk = jq * 64 + kk;
            const unsigned short* tb = hTf + (size_t)(jchunk * 16 + ch * 8) * 512 + lane * 8;

            // phase 1: batch-issue b-frags 0..3 (in flight during score compute)
            b16x8 bfv[4];
#pragma unroll
            for (int t = 0; t < 4; ++t)
                bfv[t] = __builtin_bit_cast(b16x8, *(const u16x8v*)(tb + t * 512));

            // score for 16 rows x 8 js (factored exp, no transcendentals)
            uint32_t mb0 = (md0[sub] >> (8 * g)) & 0xFFu;
            b16x8 af0;
#pragma unroll
            for (int e = 0; e < 8; ++e) {
                float2 ep = *(const float2*)&le12[(kk * 32 + 8 * g + e) * 2];
                float q0 = fmaxf(E1r0 * ep.x, E2r0 * ep.y);
                float p0 = (mb0 & (1u << e)) ? q0 : 0.f;
                lacc0 += p0;
                af0[e] = (__bf16)p0;
            }

            // mfma 0..3
#pragma unroll
            for (int t = 0; t < 4; ++t)
                acc0[t] = __builtin_amdgcn_mfma_f32_16x16x32_bf16(af0, bfv[t], acc0[t], 0, 0, 0);

            // phase 2: batch-issue b-frags 4..7, then mfma
            b16x8 bfw[4];
#pragma unroll
            for (int t = 0; t < 4; ++t)
                bfw[t] = __builtin_bit_cast(b16x8, *(const u16x8v*)(tb + (t + 4) * 512));
#pragma unroll
            for (int t = 0; t < 4; ++t)
                acc0[t + 4] = __builtin_amdgcn_mfma_f32_16x16x32_bf16(af0, bfw[t], acc0[t + 4], 0, 0, 0);
        }
    }

    // row sums over this j-quarter (lanes c,c+16,c+32,c+48 cover all g-octets)
    float l0 = lacc0 + __shfl_xor(lacc0, 16); l0 += __shfl_xor(l0, 32);
    if (ch == 0 && g == 0) rowpart[jq * N_NODES + rowbase + c] = l0;

#pragma unroll
    for (int r = 0; r < 4; ++r) {
        int grow0 = rowbase + 4 * g + r;        // C layout: row=(lane>>4)*4+reg
#pragma unroll
        for (int t = 0; t < 8; ++t) {
            pout[((size_t)jq * N_NODES + grow0) * OUT_FEAT + ch * 128 + 16 * t + c] = acc0[t][r];
        }
    }
}

// K4: out = elu( (sum_q pout[q]) / (sum_q rowpart[q]) ).
__global__ __launch_bounds__(256) void k4_reduce(const float* __restrict__ pout,
                                                 const float* __restrict__ rowpart,
                                                 float* __restrict__ out) {
    int t = blockIdx.x * 256 + threadIdx.x;
    int row = t >> 8;
    float s = 0.f, l = 0.f;
#pragma unroll
    for (int q = 0; q < 4; ++q) {
        s += pout[(size_t)q * N_NODES * OUT_FEAT + t];
        l += rowpart[q * N_NODES + row];
    }
    float inv = (l > 0.f) ? 1.0f / l : 0.f;
    float x = s * inv;
    out[t] = (x > 0.f) ? x : (__builtin_amdgcn_exp2f(x * LOG2E) - 1.0f);
}

extern "C" void kernel_launch(void* const* d_in, const int* in_sizes, int n_in,
                              void* d_out, int out_size, void* d_ws, size_t ws_size,
                              hipStream_t stream) {
    const float* input = (const float*)d_in[0];
    const int* adj = (const int*)d_in[1];
    const float* W = (const float*)d_in[2];
    const float* a_vec = (const float*)d_in[3];
    float* out = (float*)d_out;

    char* ws = (char*)d_ws;
    unsigned short* Wt  = (unsigned short*)(ws);                 // 256 KB
    unsigned short* hTf = (unsigned short*)(ws + 262144);        // 4 MB
    float*  e12     = (float*)(ws + 4456448);                    // 64 KB
    float2* row2    = (float2*)(ws + 4521984);                   // 64 KB
    float*  s1_raw  = (float*)(ws + 4587520);                    // 32 KB
    float*  s2_raw  = (float*)(ws + 4620288);                    // 32 KB
    unsigned char* bitsR = (unsigned char*)(ws + 4653056);       // 8 MB
    float*  rowpart = (float*)(ws + 13041664);                   // 128 KB
    float*  pout    = (float*)(ws + 13172736);                   // 32 MB

    hipLaunchKernelGGL(k_pack, dim3(32768), dim3(256), 0, stream, adj, bitsR);
    hipLaunchKernelGGL(k0_transpose_w, dim3(512), dim3(256), 0, stream, W, Wt);
    hipLaunchKernelGGL(k1_hgemm, dim3(N_NODES / 64), dim3(256), 0, stream,
                       input, Wt, a_vec, hTf, s1_raw, s2_raw);
    hipLaunchKernelGGL(k2_prep, dim3(32), dim3(256), 0, stream, s1_raw, s2_raw, e12, row2);
    hipLaunchKernelGGL(k3_flash, dim3(1024), dim3(256), 0, stream,
                       (const uint32_t*)bitsR, hTf, e12, row2, pout, rowpart);
    hipLaunchKernelGGL(k4_reduce, dim3(N_NODES * OUT_FEAT / 256), dim3(256), 0, stream,
                       pout, rowpart, out);
}